// Round 9
// baseline (113.063 us; speedup 1.0000x reference)
//
#include <hip/hip_runtime.h>
#include <hip/hip_bf16.h>

// ---------------------------------------------------------------------------
// KroneNet fused kernel v9 for MI355X (gfx950)
// out[i][j] = softmax_j( s_a[i] * t_j[i] )
// History: v4 46.5us / v7 50us (136 regs -> 2 waves/SIMD) / v8 ~39us
// (launch_bounds(512,4) crossed the 128-reg occupancy step; pack remap).
// Harness floor ~70us (256MB d_ws poison fill ~40us + restores) is fixed.
// v9: (a) packed-FP32 math (v_pk_fma_f32/v_pk_max_f32) via vector builtins
// for layer-1 + both epilogues (~40% VALU cut); (b) both paths resident in
// LDS (74KB, one pack, ZERO mid-kernel __syncthreads -- SA is same-wave);
// (c) W1 stored as conflict-free float2 pair-triples {w0p, w1p, b1p}.
// ---------------------------------------------------------------------------

#define BTOT 262144
#define NBLK (BTOT / 512)   // 512 blocks x 512 samples (8 waves x 64)

typedef __attribute__((ext_vector_type(2))) float floatx2;
typedef __attribute__((ext_vector_type(4))) float floatx4;
typedef __attribute__((ext_vector_type(8))) short bf16x8;
typedef __attribute__((ext_vector_type(4))) int  intx4;

// LDS layout (bytes), BOTH paths resident
#define OFF_W2  0          // 2 paths * 32768 (4 ksteps * 8 ntiles * 64 * 16B)
#define OFF_W1  65536      // 2 paths * 64 pairs * 3 float2 (24B)   = 3072
#define OFF_B2  68608      // 2 paths * 128 * float                 = 1024
#define OFF_W3A 69632      // 128 * float                           = 512
#define OFF_W3B 70144      // 3 * 128 * float                       = 1536
#define OFF_SA  71680      // 512 * float (s_a per sample)          = 2048
#define LDS_TOTAL 73728    // x2 blocks = 147456 <= 160K -> 2 blocks/CU

// pack two fp32 -> one dword of two bf16 (round-half-up), 3 VALU ops
static __device__ __forceinline__ int pack2bf(float lo, float hi) {
    unsigned a = __builtin_bit_cast(unsigned, lo) + 0x8000u;
    unsigned b = __builtin_bit_cast(unsigned, hi) + 0x8000u;
    return (int)__builtin_amdgcn_perm(b, a, 0x07060302u); // {b.hi16, a.hi16}
}

// compile-time-indexed 4-way select (NO dynamic register indexing)
#define SEL4(v, i) \
    ((i) == 0 ? (v).x : (i) == 1 ? (v).y : (i) == 2 ? (v).z : (v).w)

// 16-col butterfly reduction on a float4 (shfl per component, packed adds)
static __device__ __forceinline__ floatx4 redcol4(floatx4 v) {
    #pragma unroll
    for (int m = 1; m <= 8; m <<= 1) {
        floatx4 t;
        t.x = __shfl_xor(v.x, m);
        t.y = __shfl_xor(v.y, m);
        t.z = __shfl_xor(v.z, m);
        t.w = __shfl_xor(v.w, m);
        v = v + t;
    }
    return v;
}

static __device__ __forceinline__ floatx4 splat4(float s) {
    return (floatx4){s, s, s, s};
}

// One chunk's GEMM: acc = W2 . relu(W1.x+b1) + b2 (acc pre-init with b2).
// acc layout: (t, mt, r) -> sample mt*16+quad*4+r, n = t*16+col.
// Layer-1 in packed-f32: W1P = float2 triples {w0p, w1p, b1p} per k-pair.
#define GEMM_CHUNK(acc, XV, W1P, W2p, B2p)                                     \
    {                                                                          \
        _Pragma("unroll")                                                      \
        for (int t = 0; t < 8; ++t) {                                          \
            float b2n = (B2p)[t * 16 + col];                                   \
            floatx4 bi = splat4(b2n);                                          \
            _Pragma("unroll")                                                  \
            for (int mt = 0; mt < 2; ++mt) acc[t][mt] = bi;                    \
        }                                                                      \
        _Pragma("unroll")                                                      \
        for (int s = 0; s < 4; ++s) {                                          \
            intx4 af[2];                                                       \
            _Pragma("unroll")                                                  \
            for (int j2 = 0; j2 < 4; ++j2) {                                   \
                int kp = s * 16 + quad * 4 + j2;                               \
                floatx2 w0p = (W1P)[kp * 3];                                   \
                floatx2 w1p = (W1P)[kp * 3 + 1];                               \
                floatx2 b1p = (W1P)[kp * 3 + 2];                               \
                _Pragma("unroll")                                              \
                for (int mt = 0; mt < 2; ++mt) {                               \
                    floatx2 xx = (floatx2){(XV)[mt].x, (XV)[mt].x};            \
                    floatx2 xy = (floatx2){(XV)[mt].y, (XV)[mt].y};            \
                    floatx2 h = __builtin_elementwise_fma(xx, w0p,             \
                                  __builtin_elementwise_fma(xy, w1p, b1p));    \
                    h = __builtin_elementwise_max(h, (floatx2){0.f, 0.f});     \
                    af[mt][j2] = pack2bf(h.x, h.y);                            \
                }                                                              \
            }                                                                  \
            _Pragma("unroll")                                                  \
            for (int t = 0; t < 8; ++t) {                                      \
                bf16x8 bfr = (W2p)[(s * 8 + t) * 64 + lane];                   \
                _Pragma("unroll")                                              \
                for (int mt = 0; mt < 2; ++mt)                                 \
                    acc[t][mt] = __builtin_amdgcn_mfma_f32_16x16x32_bf16(      \
                        __builtin_bit_cast(bf16x8, af[mt]), bfr,               \
                        acc[t][mt], 0, 0, 0);                                  \
            }                                                                  \
        }                                                                      \
    }

// ---------------------------------------------------------------------------
// 512 blocks x 512 threads (8 waves). Per block (512 samples):
//   pack both paths -> ONE __syncthreads -> phase a (s_a -> LDS, same-wave)
//   -> phase b (t_j + softmax + store), no further block syncs.
// W2 mapping (verified v5-v8): float4 group (n, k4), k = 4*k4:
// dest = path*32768 + (s*8 + (n>>4))*1024 + l*16 + (k&7)*2,
// s = k>>5, l = ((k&31)>>3)*16 + (n&15). B-frag: lane = quad*16+col holds
// B[k=quad*8+j][n=col].
// ---------------------------------------------------------------------------
__global__ __launch_bounds__(512, 4)
void krone_fused(const float* __restrict__ x,
                 const float* __restrict__ w1a, const float* __restrict__ w1b,
                 const float* __restrict__ b1a, const float* __restrict__ b1b,
                 const float* __restrict__ w2a, const float* __restrict__ w2b,
                 const float* __restrict__ b2a, const float* __restrict__ b2b,
                 const float* __restrict__ w3a, const float* __restrict__ w3b,
                 const float* __restrict__ b3a, const float* __restrict__ b3b,
                 float* __restrict__ out) {
    __shared__ __align__(16) unsigned char smem[LDS_TOTAL];

    const int tid  = threadIdx.x;
    const int lane = tid & 63;
    const int wave = tid >> 6;
    const int quad = lane >> 4;
    const int col  = lane & 15;
    const int wbase = blockIdx.x * 512 + wave * 64;   // this wave's 64 samples

    // ---- pack both paths into LDS ----
    {
        #pragma unroll
        for (int i = 0; i < 16; ++i) {
            const int path = i >> 3;
            const float4* w2p = (const float4*)(path ? w2b : w2a);
            int n  = (tid & 15) | ((i & 7) << 4);
            int k4 = tid >> 4;                         // 0..31
            float4 f = w2p[n * 32 + k4];
            int k = k4 * 4;
            int s = k >> 5;
            int j0 = k & 7;                            // 0 or 4
            int l = ((k & 31) >> 3) * 16 + (n & 15);
            int2 pkd;
            pkd.x = pack2bf(f.x, f.y);
            pkd.y = pack2bf(f.z, f.w);
            *(int2*)(smem + OFF_W2 + path * 32768 +
                     (s * 8 + (n >> 4)) * 1024 + l * 16 + j0 * 2) = pkd;
        }
        if (tid < 128) {
            // W1 pair-triples: p = tid>>6, kp = tid&63
            int p = tid >> 6, kp = tid & 63;
            const float* w1 = p ? w1b : w1a;
            const float* b1 = p ? b1b : b1a;
            float4 w4 = ((const float4*)w1)[kp];       // w1[4kp..4kp+3]
            floatx2* dst = (floatx2*)(smem + OFF_W1) + p * 192 + kp * 3;
            dst[0] = (floatx2){w4.x, w4.z};            // x-coeff of k0,k1
            dst[1] = (floatx2){w4.y, w4.w};            // y-coeff
            dst[2] = (floatx2){b1[2 * kp], b1[2 * kp + 1]};
            ((float*)(smem + OFF_B2))[tid] = b2a[tid];
            ((float*)(smem + OFF_W3A))[tid] = w3a[tid];
        } else if (tid < 256) {
            ((float*)(smem + OFF_B2))[tid] = b2b[tid - 128];
        }
        if (tid >= 128)   // 384 entries of w3b
            ((float*)(smem + OFF_W3B))[tid - 128] = w3b[tid - 128];
    }

    const bf16x8*  W2A = (const bf16x8*)(smem + OFF_W2);
    const bf16x8*  W2B = (const bf16x8*)(smem + OFF_W2 + 32768);
    const floatx2* W1A = (const floatx2*)(smem + OFF_W1);
    const floatx2* W1B = W1A + 192;
    const float*   B2A = (const float*)(smem + OFF_B2);
    const float*   B2B = B2A + 128;
    const float*   W3A = (const float*)(smem + OFF_W3A);
    const float*   W3B = (const float*)(smem + OFF_W3B);
    float*         SA  = (float*)(smem + OFF_SA);
    const float2*  xA  = (const float2*)x;
    const float2*  xB  = xA + BTOT;

    const float b3a_ = b3a[0];                         // uniform -> SGPR
    const float b30 = b3b[0], b31 = b3b[1], b32 = b3b[2];

    // ---- phase a: x loads issued before the barrier to hide latency ----
    float2 xv[4];   // [c*2+mt]
    #pragma unroll
    for (int c = 0; c < 2; ++c)
        #pragma unroll
        for (int mt = 0; mt < 2; ++mt)
            xv[c * 2 + mt] = xA[wbase + c * 32 + mt * 16 + col];

    __syncthreads();   // the ONLY block-wide barrier

    #pragma unroll
    for (int c = 0; c < 2; ++c) {
        __builtin_amdgcn_sched_barrier(0);
        floatx4 acc[8][2];
        GEMM_CHUNK(acc, xv + 2 * c, W1A, W2A, B2A);
        __builtin_amdgcn_sched_barrier(0);

        floatx4 pa[2] = {(floatx4){0.f,0.f,0.f,0.f}, (floatx4){0.f,0.f,0.f,0.f}};
        #pragma unroll
        for (int t = 0; t < 8; ++t) {
            floatx4 w4 = splat4(W3A[t * 16 + col]);
            #pragma unroll
            for (int mt = 0; mt < 2; ++mt) {
                floatx4 h = __builtin_elementwise_max(acc[t][mt],
                                                      (floatx4){0.f,0.f,0.f,0.f});
                pa[mt] = __builtin_elementwise_fma(w4, h, pa[mt]);
            }
        }
        #pragma unroll
        for (int mt = 0; mt < 2; ++mt) pa[mt] = redcol4(pa[mt]);
        __builtin_amdgcn_sched_barrier(0);

        if (col < 4) {
            #pragma unroll
            for (int mt = 0; mt < 2; ++mt) {
                int sl = mt * 16 + quad * 4 + col;
                SA[wave * 64 + c * 32 + sl] = SEL4(pa[mt], col) + b3a_;
            }
        }
        __builtin_amdgcn_sched_barrier(0);
    }

    // ---- phase b: reload x; SA read is same-wave (lgkmcnt-ordered) ----
    #pragma unroll
    for (int c = 0; c < 2; ++c)
        #pragma unroll
        for (int mt = 0; mt < 2; ++mt)
            xv[c * 2 + mt] = xB[wbase + c * 32 + mt * 16 + col];

    #pragma unroll
    for (int c = 0; c < 2; ++c) {
        __builtin_amdgcn_sched_barrier(0);
        floatx4 acc[8][2];
        GEMM_CHUNK(acc, xv + 2 * c, W1B, W2B, B2B);
        __builtin_amdgcn_sched_barrier(0);

        #pragma unroll
        for (int mt = 0; mt < 2; ++mt) {     // per-mt to cap live partials
            floatx4 p0 = (floatx4){0.f,0.f,0.f,0.f};
            floatx4 p1 = p0, p2 = p0;
            #pragma unroll
            for (int t = 0; t < 8; ++t) {
                int n = t * 16 + col;
                floatx4 h = __builtin_elementwise_max(acc[t][mt],
                                                      (floatx4){0.f,0.f,0.f,0.f});
                p0 = __builtin_elementwise_fma(splat4(W3B[n]),       h, p0);
                p1 = __builtin_elementwise_fma(splat4(W3B[128 + n]), h, p1);
                p2 = __builtin_elementwise_fma(splat4(W3B[256 + n]), h, p2);
            }
            p0 = redcol4(p0); p1 = redcol4(p1); p2 = redcol4(p2);
            if (col < 4) {
                int sl = mt * 16 + quad * 4 + col;
                float t0 = SEL4(p0, col) + b30;
                float t1 = SEL4(p1, col) + b31;
                float t2 = SEL4(p2, col) + b32;
                float sa = SA[wave * 64 + c * 32 + sl];
                float y0 = sa * t0, y1 = sa * t1, y2 = sa * t2;
                float m = fmaxf(y0, fmaxf(y1, y2));
                float e0 = __expf(y0 - m), e1 = __expf(y1 - m), e2 = __expf(y2 - m);
                float rs = 1.f / (e0 + e1 + e2);
                long o = (long)(wbase + c * 32 + sl) * 3;
                out[o]     = e0 * rs;
                out[o + 1] = e1 * rs;
                out[o + 2] = e2 * rs;
            }
        }
        __builtin_amdgcn_sched_barrier(0);
    }
}

extern "C" void kernel_launch(void* const* d_in, const int* in_sizes, int n_in,
                              void* d_out, int out_size, void* d_ws, size_t ws_size,
                              hipStream_t stream) {
    const float* x   = (const float*)d_in[0];
    const float* w1a = (const float*)d_in[1];
    const float* w1b = (const float*)d_in[2];
    const float* b1a = (const float*)d_in[3];
    const float* b1b = (const float*)d_in[4];
    const float* w2a = (const float*)d_in[5];
    const float* w2b = (const float*)d_in[6];
    const float* b2a = (const float*)d_in[7];
    const float* b2b = (const float*)d_in[8];
    const float* w3a = (const float*)d_in[9];
    const float* w3b = (const float*)d_in[10];
    const float* b3a = (const float*)d_in[11];
    const float* b3b = (const float*)d_in[12];
    float* out = (float*)d_out;

    krone_fused<<<NBLK, 512, 0, stream>>>(x, w1a, w1b, b1a, b1b, w2a, w2b,
                                          b2a, b2b, w3a, w3b, b3a, b3b, out);
}